// Round 13
// baseline (117.284 us; speedup 1.0000x reference)
//
#include <hip/hip_runtime.h>
#include <math.h>

// Problem dims (fixed by setup_inputs)
constexpr int B = 8;
constexpr int A = 49104;
constexpr int C = 80;       // classes
constexpr int M = 32;       // max annotations
constexpr int TILE = 256;
constexpr int NTILES = (A + TILE - 1) / TILE;  // 192
constexpr int QPA = C / 4;                     // 20 float4 per anchor
constexpr int QPI = A * C / 4;                 // 982080 float4 per image
constexpr int SBLK = 480;                      // stream blocks per image
constexpr int SCHUNK = QPI / SBLK;             // 2046 float4 per block (exact)

// ws layout (floats): [0..7]=cls_sum (log2 units), [8..15]=reg_sum, [16..23]=npos
__global__ void init_ws_kernel(float* ws) {
    int t = threadIdx.x;
    if (t < 24) ws[t] = 0.0f;
}

// Unweighted focal "else" term: f(p) = p^2 * (-log2(1-p)), med3-clamped.
__device__ __forceinline__ void fquad(const float4 p4, float& a0, float& a1) {
    const float px = __builtin_amdgcn_fmed3f(p4.x, 1e-4f, 1.0f - 1e-4f);
    const float py = __builtin_amdgcn_fmed3f(p4.y, 1e-4f, 1.0f - 1e-4f);
    const float pz = __builtin_amdgcn_fmed3f(p4.z, 1e-4f, 1.0f - 1e-4f);
    const float pw = __builtin_amdgcn_fmed3f(p4.w, 1e-4f, 1.0f - 1e-4f);
    a0 = fmaf(px * px, -__log2f(1.0f - px), a0);
    a1 = fmaf(py * py, -__log2f(1.0f - py), a1);
    a0 = fmaf(pz * pz, -__log2f(1.0f - pz), a0);
    a1 = fmaf(pw * pw, -__log2f(1.0f - pw), a1);
}

// K2: pure streaming focal sum over ALL elements (weight-free; ignore rows
// are subtracted by the assign kernel). Fill-kernel-shaped: 1D-flat dense
// grid, single-basic-block loop, no upstream phases. This is the structural
// A/B vs R4-R12's per-(b,tile) kernel that was pinned at 1.7 TB/s.
__global__ __launch_bounds__(256) void stream_kernel(
    const float* __restrict__ cls, float* __restrict__ ws)
{
    const int b = blockIdx.y;
    const float4* __restrict__ cp =
        (const float4*)cls + (size_t)b * QPI + (size_t)blockIdx.x * SCHUNK;
    float a0 = 0.0f, a1 = 0.0f;
    #pragma unroll 4
    for (int k = threadIdx.x; k < SCHUNK; k += 256) fquad(cp[k], a0, a1);
    float v = a0 + a1;
    for (int off = 32; off > 0; off >>= 1) v += __shfl_down(v, off, 64);
    __shared__ float red[4];
    if ((threadIdx.x & 63) == 0) red[threadIdx.x >> 6] = v;
    __syncthreads();
    if (threadIdx.x == 0)
        atomicAdd(&ws[b], 0.75f * (red[0] + red[1] + red[2] + red[3]));
}

// K1: per-anchor assignment + rare-path corrections. Runs AFTER the
// streamer so the scattered ignore-row re-reads hit warm L3.
__global__ __launch_bounds__(TILE) void assign_kernel(
    const float* __restrict__ cls,      // (B, A, C)
    const float* __restrict__ reg,      // (B, A, 4)
    const float* __restrict__ anchors,  // (A, 4)  y1,x1,y2,x2
    const float* __restrict__ ann,      // (B, M, 5) x1,y1,x2,y2,label
    float* __restrict__ ws)
{
    __shared__ float s_bx1[M], s_by1[M], s_bx2[M], s_by2[M], s_area[M], s_lab[M];
    __shared__ float s_red[3][4];

    const int t    = threadIdx.x;
    const int tile = blockIdx.x;
    const int b    = blockIdx.y;
    const int base = tile * TILE;
    const int nA   = min(TILE, A - base);

    // Invalid boxes -> degenerate (zero overlap, +inf area): IoU loop needs
    // no validity test; invalid labels trail valid ones so argmax semantics
    // are preserved (verified: absmax 0.0 in R9/R12).
    if (t < M) {
        const float x1 = ann[(b * M + t) * 5 + 0];
        const float y1 = ann[(b * M + t) * 5 + 1];
        const float x2 = ann[(b * M + t) * 5 + 2];
        const float y2 = ann[(b * M + t) * 5 + 3];
        const float lb = ann[(b * M + t) * 5 + 4];
        const bool v = (lb != -1.0f);
        s_bx1[t]  = v ? x1 :  3e18f;
        s_by1[t]  = v ? y1 :  3e18f;
        s_bx2[t]  = v ? x2 : -3e18f;
        s_by2[t]  = v ? y2 : -3e18f;
        s_area[t] = v ? (x2 - x1) * (y2 - y1) : __builtin_inff();
        s_lab[t]  = lb;
    }
    const float4 an = ((const float4*)anchors)[min(base + t, A - 1)];  // y1,x1,y2,x2
    __syncthreads();

    // Phase A: division-free band classification.
    const float aw  = an.w - an.y;
    const float ah  = an.z - an.x;
    const float aarea = ah * aw;
    float e4 = -1.0f, e5 = -1.0f;   // max_j (inter - thr*ua); <0 => iou_max < thr
    if (t < nA) {
        #pragma unroll
        for (int j = 0; j < M; ++j) {
            float iw = fmaxf(fminf(an.w, s_bx2[j]) - fmaxf(an.y, s_bx1[j]), 0.0f);
            float ih = fmaxf(fminf(an.z, s_by2[j]) - fmaxf(an.x, s_by1[j]), 0.0f);
            const float inter = iw * ih;
            const float ua = aarea + s_area[j] - inter;   // >=256, clamp never binds
            e4 = fmaxf(e4, fmaf(-0.4f, ua, inter));
            e5 = fmaxf(e5, fmaf(-0.5f, ua, inter));
        }
    }
    const bool pos = (t < nA) && (e5 >= 0.0f);
    const bool ign = (t < nA) && (e4 >= 0.0f) && !pos;   // 0.4 <= iou_max < 0.5

    // Rare pos re-pass: precise argmax + label correction + smooth-L1.
    float cls_part = 0.0f, reg_part = 0.0f, npos_part = 0.0f;
    if (pos) {
        npos_part = 1.0f;
        float best = -2.0f; int arg = 0;
        for (int j = 0; j < M; ++j) {
            float iw = fmaxf(fminf(an.w, s_bx2[j]) - fmaxf(an.y, s_bx1[j]), 0.0f);
            float ih = fmaxf(fminf(an.z, s_by2[j]) - fmaxf(an.x, s_by1[j]), 0.0f);
            const float inter = iw * ih;
            const float ua = fmaxf(aarea + s_area[j] - inter, 1e-8f);
            const float iou = inter / ua;                 // invalid j: 0/inf = 0
            if (iou > best) { best = iou; arg = j; }
        }
        const int lab = (int)s_lab[arg];
        const float pl = fminf(fmaxf(cls[((size_t)b * A + base + t) * C + lab], 1e-4f), 1.0f - 1e-4f);
        const float ql = 1.0f - pl;
        // then-term minus the 0.75*f else-term the streamer blindly added
        cls_part = -0.25f * ql * ql * __log2f(pl) + 0.75f * pl * pl * __log2f(ql);

        const float4 r = ((const float4*)reg)[(size_t)b * A + base + t];
        const float gx1 = s_bx1[arg], gy1 = s_by1[arg];
        const float gx2 = s_bx2[arg], gy2 = s_by2[arg];
        float gw = gx2 - gx1;
        float gh = gy2 - gy1;
        const float gcx = gx1 + 0.5f * gw;
        const float gcy = gy1 + 0.5f * gh;
        const float acx = an.y + 0.5f * aw;
        const float acy = an.x + 0.5f * ah;
        gw = fmaxf(gw, 1.0f);
        gh = fmaxf(gh, 1.0f);
        const float t0 = (gcy - acy) / ah;
        const float t1 = (gcx - acx) / aw;
        const float t2 = __logf(gh / ah);
        const float t3 = __logf(gw / aw);
        const float d0 = fabsf(t0 - r.x);
        const float d1 = fabsf(t1 - r.y);
        const float d2 = fabsf(t2 - r.z);
        const float d3 = fabsf(t3 - r.w);
        const float TH = 1.0f / 9.0f;
        const float SH = 0.5f / 9.0f;
        reg_part = ((d0 <= TH) ? 4.5f * d0 * d0 : d0 - SH)
                 + ((d1 <= TH) ? 4.5f * d1 * d1 : d1 - SH)
                 + ((d2 <= TH) ? 4.5f * d2 * d2 : d2 - SH)
                 + ((d3 <= TH) ? 4.5f * d3 * d3 : d3 - SH);
    }

    // Ignore anchors: subtract their row (streamer added it; L3-warm).
    if (ign) {
        const float4* rp = (const float4*)(cls + ((size_t)b * A + base) * C) + t * QPA;
        float g0 = 0.0f, g1 = 0.0f;
        #pragma unroll
        for (int j = 0; j < QPA; ++j) fquad(rp[j], g0, g1);
        cls_part = -0.75f * (g0 + g1);
    }

    // Block reduction: wave shuffle then cross-wave via LDS.
    for (int off = 32; off > 0; off >>= 1) {
        cls_part  += __shfl_down(cls_part,  off, 64);
        reg_part  += __shfl_down(reg_part,  off, 64);
        npos_part += __shfl_down(npos_part, off, 64);
    }
    const int wave = t >> 6;
    const int lane = t & 63;
    if (lane == 0) {
        s_red[0][wave] = cls_part;
        s_red[1][wave] = reg_part;
        s_red[2][wave] = npos_part;
    }
    __syncthreads();
    if (t == 0) {
        float cs = 0.0f, rs = 0.0f, ns = 0.0f;
        #pragma unroll
        for (int wv = 0; wv < 4; ++wv) {
            cs += s_red[0][wv];
            rs += s_red[1][wv];
            ns += s_red[2][wv];
        }
        atomicAdd(&ws[b],      cs);
        atomicAdd(&ws[8 + b],  rs);
        atomicAdd(&ws[16 + b], ns);
    }
}

__global__ void finalize_kernel(const float* __restrict__ ws,
                                const float* __restrict__ ann,
                                float* __restrict__ out)
{
    const int t = threadIdx.x;  // 64 threads, one wave
    float cls_v = 0.0f, reg_v = 0.0f;
    if (t < B) {
        bool has_valid = false;
        for (int m = 0; m < M; ++m)
            has_valid = has_valid || (ann[t * M * 5 + m * 5 + 4] != -1.0f);
        const float npos = ws[16 + t];
        // cls accumulator is in log2 units -> scale by ln(2)
        const float cs = 0.69314718056f * ws[t] / fmaxf(npos, 1.0f);
        cls_v = has_valid ? cs : 0.0f;
        reg_v = (npos > 0.0f) ? (ws[8 + t] / fmaxf(npos * 4.0f, 1.0f)) : 0.0f;
    }
    for (int off = 32; off > 0; off >>= 1) {
        cls_v += __shfl_down(cls_v, off, 64);
        reg_v += __shfl_down(reg_v, off, 64);
    }
    if (t == 0) {
        out[0] = cls_v * (1.0f / (float)B);
        out[1] = reg_v * (1.0f / (float)B);
    }
}

extern "C" void kernel_launch(void* const* d_in, const int* in_sizes, int n_in,
                              void* d_out, int out_size, void* d_ws, size_t ws_size,
                              hipStream_t stream) {
    const float* cls     = (const float*)d_in[0];
    const float* reg     = (const float*)d_in[1];
    const float* anchors = (const float*)d_in[2];
    const float* ann     = (const float*)d_in[3];
    float* out = (float*)d_out;
    float* ws  = (float*)d_ws;

    init_ws_kernel<<<1, 32, 0, stream>>>(ws);
    stream_kernel<<<dim3(SBLK, B), 256, 0, stream>>>(cls, ws);
    assign_kernel<<<dim3(NTILES, B), TILE, 0, stream>>>(cls, reg, anchors, ann, ws);
    finalize_kernel<<<1, 64, 0, stream>>>(ws, ann, out);
}

// Round 15
// 87.737 us; speedup vs baseline: 1.3368x; 1.3368x over previous
//
#include <hip/hip_runtime.h>
#include <math.h>

// Problem dims (fixed by setup_inputs)
constexpr int B = 8;
constexpr int A = 49104;
constexpr int C = 80;       // classes
constexpr int M = 32;       // max annotations
constexpr int TILE = 256;
constexpr int NTILES = (A + TILE - 1) / TILE;  // 192
constexpr int QPA = C / 4;                     // 20 float4 per anchor
constexpr int QPI = A * C / 4;                 // 982080 float4 per image
constexpr int SPB  = 256;                      // stream blocks per image
constexpr int NSTREAM = SPB * B;               // 2048 stream blocks (8/CU)
constexpr int NASSIGN = NTILES * B;            // 1536 assign blocks
constexpr int SSTRIDE = SPB * 256;             // 65536 threads per image stream

typedef float v4f __attribute__((ext_vector_type(4)));  // native vec for nontemporal builtin

// ws layout (floats): [0..7]=cls_sum (log2 units), [8..15]=reg_sum, [16..23]=npos
__global__ void init_ws_kernel(float* ws) {
    int t = threadIdx.x;
    if (t < 24) ws[t] = 0.0f;
}

// Unweighted focal "else" term: f(p) = p^2 * (-log2(1-p)), med3-clamped.
__device__ __forceinline__ void fquad4(const float x, const float y,
                                       const float z, const float w,
                                       float& a0, float& a1) {
    const float px = __builtin_amdgcn_fmed3f(x, 1e-4f, 1.0f - 1e-4f);
    const float py = __builtin_amdgcn_fmed3f(y, 1e-4f, 1.0f - 1e-4f);
    const float pz = __builtin_amdgcn_fmed3f(z, 1e-4f, 1.0f - 1e-4f);
    const float pw = __builtin_amdgcn_fmed3f(w, 1e-4f, 1.0f - 1e-4f);
    a0 = fmaf(px * px, -__log2f(1.0f - px), a0);
    a1 = fmaf(py * py, -__log2f(1.0f - py), a1);
    a0 = fmaf(pz * pz, -__log2f(1.0f - pz), a0);
    a1 = fmaf(pw * pw, -__log2f(1.0f - pw), a1);
}
__device__ __forceinline__ void fquad(const float4 p, float& a0, float& a1) {
    fquad4(p.x, p.y, p.z, p.w, a0, a1);
}

// Role-partitioned combo kernel: blocks [0,NSTREAM) stream the whole cls
// array (full occupancy, nontemporal loads); blocks [NSTREAM, NSTREAM+NASSIGN)
// do the per-anchor assignment + rare corrections CONCURRENTLY (R13 showed
// serializing them costs ~45 us; their latency hides in the stream's stalls).
__global__ __launch_bounds__(256) void combo_kernel(
    const float* __restrict__ cls,      // (B, A, C)
    const float* __restrict__ reg,      // (B, A, 4)
    const float* __restrict__ anchors,  // (A, 4)  y1,x1,y2,x2
    const float* __restrict__ ann,      // (B, M, 5) x1,y1,x2,y2,label
    float* __restrict__ ws)
{
    const int t = threadIdx.x;

    if (blockIdx.x < (unsigned)NSTREAM) {
        // ---------------- STREAM ROLE ----------------
        const int b   = blockIdx.x >> 8;          // 256 blocks per image
        const int blk = blockIdx.x & 255;
        const v4f* __restrict__ cp = (const v4f*)cls + (size_t)b * QPI;
        float a0 = 0.0f, a1 = 0.0f;
        #pragma unroll 4
        for (int k = blk * 256 + t; k < QPI; k += SSTRIDE) {
            const v4f p = __builtin_nontemporal_load(cp + k);
            fquad4(p.x, p.y, p.z, p.w, a0, a1);
        }
        float v = a0 + a1;
        for (int off = 32; off > 0; off >>= 1) v += __shfl_down(v, off, 64);
        __shared__ float red[4];
        if ((t & 63) == 0) red[t >> 6] = v;
        __syncthreads();
        if (t == 0)
            atomicAdd(&ws[b], 0.75f * (red[0] + red[1] + red[2] + red[3]));
        return;
    }

    // ---------------- ASSIGN ROLE ----------------
    __shared__ float s_bx1[M], s_by1[M], s_bx2[M], s_by2[M], s_area[M], s_lab[M];
    __shared__ float s_red[3][4];

    const int abid = blockIdx.x - NSTREAM;
    const int b    = abid / NTILES;
    const int tile = abid - b * NTILES;
    const int base = tile * TILE;
    const int nA   = min(TILE, A - base);

    if (t < M) {
        const float x1 = ann[(b * M + t) * 5 + 0];
        const float y1 = ann[(b * M + t) * 5 + 1];
        const float x2 = ann[(b * M + t) * 5 + 2];
        const float y2 = ann[(b * M + t) * 5 + 3];
        const float lb = ann[(b * M + t) * 5 + 4];
        const bool v = (lb != -1.0f);
        s_bx1[t]  = v ? x1 :  3e18f;
        s_by1[t]  = v ? y1 :  3e18f;
        s_bx2[t]  = v ? x2 : -3e18f;
        s_by2[t]  = v ? y2 : -3e18f;
        s_area[t] = v ? (x2 - x1) * (y2 - y1) : __builtin_inff();
        s_lab[t]  = lb;
    }
    const float4 an = ((const float4*)anchors)[min(base + t, A - 1)];  // y1,x1,y2,x2
    __syncthreads();

    // Phase A: division-free band classification.
    const float aw  = an.w - an.y;
    const float ah  = an.z - an.x;
    const float aarea = ah * aw;
    float e4 = -1.0f, e5 = -1.0f;
    if (t < nA) {
        #pragma unroll
        for (int j = 0; j < M; ++j) {
            float iw = fmaxf(fminf(an.w, s_bx2[j]) - fmaxf(an.y, s_bx1[j]), 0.0f);
            float ih = fmaxf(fminf(an.z, s_by2[j]) - fmaxf(an.x, s_by1[j]), 0.0f);
            const float inter = iw * ih;
            const float ua = aarea + s_area[j] - inter;
            e4 = fmaxf(e4, fmaf(-0.4f, ua, inter));
            e5 = fmaxf(e5, fmaf(-0.5f, ua, inter));
        }
    }
    const bool pos = (t < nA) && (e5 >= 0.0f);
    const bool ign = (t < nA) && (e4 >= 0.0f) && !pos;

    float cls_part = 0.0f, reg_part = 0.0f, npos_part = 0.0f;
    if (pos) {
        npos_part = 1.0f;
        float best = -2.0f; int arg = 0;
        for (int j = 0; j < M; ++j) {
            float iw = fmaxf(fminf(an.w, s_bx2[j]) - fmaxf(an.y, s_bx1[j]), 0.0f);
            float ih = fmaxf(fminf(an.z, s_by2[j]) - fmaxf(an.x, s_by1[j]), 0.0f);
            const float inter = iw * ih;
            const float ua = fmaxf(aarea + s_area[j] - inter, 1e-8f);
            const float iou = inter / ua;
            if (iou > best) { best = iou; arg = j; }
        }
        const int lab = (int)s_lab[arg];
        const float pl = fminf(fmaxf(cls[((size_t)b * A + base + t) * C + lab], 1e-4f), 1.0f - 1e-4f);
        const float ql = 1.0f - pl;
        // then-term minus the 0.75*f else-term the streamer blindly adds
        cls_part = -0.25f * ql * ql * __log2f(pl) + 0.75f * pl * pl * __log2f(ql);

        const float4 r = ((const float4*)reg)[(size_t)b * A + base + t];
        const float gx1 = s_bx1[arg], gy1 = s_by1[arg];
        const float gx2 = s_bx2[arg], gy2 = s_by2[arg];
        float gw = gx2 - gx1;
        float gh = gy2 - gy1;
        const float gcx = gx1 + 0.5f * gw;
        const float gcy = gy1 + 0.5f * gh;
        const float acx = an.y + 0.5f * aw;
        const float acy = an.x + 0.5f * ah;
        gw = fmaxf(gw, 1.0f);
        gh = fmaxf(gh, 1.0f);
        const float t0 = (gcy - acy) / ah;
        const float t1 = (gcx - acx) / aw;
        const float t2 = __logf(gh / ah);
        const float t3 = __logf(gw / aw);
        const float d0 = fabsf(t0 - r.x);
        const float d1 = fabsf(t1 - r.y);
        const float d2 = fabsf(t2 - r.z);
        const float d3 = fabsf(t3 - r.w);
        const float TH = 1.0f / 9.0f;
        const float SH = 0.5f / 9.0f;
        reg_part = ((d0 <= TH) ? 4.5f * d0 * d0 : d0 - SH)
                 + ((d1 <= TH) ? 4.5f * d1 * d1 : d1 - SH)
                 + ((d2 <= TH) ? 4.5f * d2 * d2 : d2 - SH)
                 + ((d3 <= TH) ? 4.5f * d3 * d3 : d3 - SH);
    }

    // Ignore anchors: subtract their row (streamer adds it unconditionally).
    if (ign) {
        const float4* rp = (const float4*)(cls + ((size_t)b * A + base) * C) + t * QPA;
        float g0 = 0.0f, g1 = 0.0f;
        #pragma unroll
        for (int j = 0; j < QPA; ++j) fquad(rp[j], g0, g1);
        cls_part = -0.75f * (g0 + g1);
    }

    for (int off = 32; off > 0; off >>= 1) {
        cls_part  += __shfl_down(cls_part,  off, 64);
        reg_part  += __shfl_down(reg_part,  off, 64);
        npos_part += __shfl_down(npos_part, off, 64);
    }
    const int wave = t >> 6;
    const int lane = t & 63;
    if (lane == 0) {
        s_red[0][wave] = cls_part;
        s_red[1][wave] = reg_part;
        s_red[2][wave] = npos_part;
    }
    __syncthreads();
    if (t == 0) {
        float cs = 0.0f, rs = 0.0f, ns = 0.0f;
        #pragma unroll
        for (int wv = 0; wv < 4; ++wv) {
            cs += s_red[0][wv];
            rs += s_red[1][wv];
            ns += s_red[2][wv];
        }
        atomicAdd(&ws[b],      cs);
        atomicAdd(&ws[8 + b],  rs);
        atomicAdd(&ws[16 + b], ns);
    }
}

__global__ void finalize_kernel(const float* __restrict__ ws,
                                const float* __restrict__ ann,
                                float* __restrict__ out)
{
    const int t = threadIdx.x;  // 64 threads, one wave
    float cls_v = 0.0f, reg_v = 0.0f;
    if (t < B) {
        bool has_valid = false;
        for (int m = 0; m < M; ++m)
            has_valid = has_valid || (ann[t * M * 5 + m * 5 + 4] != -1.0f);
        const float npos = ws[16 + t];
        // cls accumulator is in log2 units -> scale by ln(2)
        const float cs = 0.69314718056f * ws[t] / fmaxf(npos, 1.0f);
        cls_v = has_valid ? cs : 0.0f;
        reg_v = (npos > 0.0f) ? (ws[8 + t] / fmaxf(npos * 4.0f, 1.0f)) : 0.0f;
    }
    for (int off = 32; off > 0; off >>= 1) {
        cls_v += __shfl_down(cls_v, off, 64);
        reg_v += __shfl_down(reg_v, off, 64);
    }
    if (t == 0) {
        out[0] = cls_v * (1.0f / (float)B);
        out[1] = reg_v * (1.0f / (float)B);
    }
}

extern "C" void kernel_launch(void* const* d_in, const int* in_sizes, int n_in,
                              void* d_out, int out_size, void* d_ws, size_t ws_size,
                              hipStream_t stream) {
    const float* cls     = (const float*)d_in[0];
    const float* reg     = (const float*)d_in[1];
    const float* anchors = (const float*)d_in[2];
    const float* ann     = (const float*)d_in[3];
    float* out = (float*)d_out;
    float* ws  = (float*)d_ws;

    init_ws_kernel<<<1, 32, 0, stream>>>(ws);
    combo_kernel<<<NSTREAM + NASSIGN, 256, 0, stream>>>(cls, reg, anchors, ann, ws);
    finalize_kernel<<<1, 64, 0, stream>>>(ws, ann, out);
}

// Round 16
// 66.175 us; speedup vs baseline: 1.7723x; 1.3258x over previous
//
#include <hip/hip_runtime.h>
#include <math.h>

// Problem dims (fixed by setup_inputs)
constexpr int B = 8;
constexpr int A = 49104;
constexpr int C = 80;       // classes
constexpr int M = 32;       // max annotations
constexpr int TILE = 256;
constexpr int NTILES = (A + TILE - 1) / TILE;  // 192
constexpr int QPA = C / 4;                     // 20 float4 per anchor
constexpr int SLOTS = 4;                       // per-wave DMA pipeline depth

#define SBAR() __builtin_amdgcn_sched_barrier(0)

// ws layout (floats): [0..7]=cls_sum (log2 units), [8..15]=reg_sum, [16..23]=npos
__global__ void init_ws_kernel(float* ws) {
    int t = threadIdx.x;
    if (t < 24) ws[t] = 0.0f;
}

// Unweighted focal "else" term: f(p) = p^2 * (-log2(1-p)), med3-clamped.
__device__ __forceinline__ void fquad(const float4 p4, float& a0, float& a1) {
    const float px = __builtin_amdgcn_fmed3f(p4.x, 1e-4f, 1.0f - 1e-4f);
    const float py = __builtin_amdgcn_fmed3f(p4.y, 1e-4f, 1.0f - 1e-4f);
    const float pz = __builtin_amdgcn_fmed3f(p4.z, 1e-4f, 1.0f - 1e-4f);
    const float pw = __builtin_amdgcn_fmed3f(p4.w, 1e-4f, 1.0f - 1e-4f);
    a0 = fmaf(px * px, -__log2f(1.0f - px), a0);
    a1 = fmaf(py * py, -__log2f(1.0f - py), a1);
    a0 = fmaf(pz * pz, -__log2f(1.0f - pz), a0);
    a1 = fmaf(pw * pw, -__log2f(1.0f - pw), a1);
}

// Async global->LDS DMA, 16B per lane. No VGPR destination => the compiler
// cannot collapse (R9), spill (R11), or sink (R12) the pipeline. LDS dest is
// wave-uniform base; HW writes base + lane*16. Global src is per-lane.
__device__ __forceinline__ void gload_lds16(const float4* src, float* lds_dst) {
    __builtin_amdgcn_global_load_lds(
        (const __attribute__((address_space(1))) void*)src,
        (__attribute__((address_space(3))) void*)lds_dst,
        16, 0, 0);
}

__global__ __launch_bounds__(TILE) void focal_main_kernel(
    const float* __restrict__ cls,      // (B, A, C)
    const float* __restrict__ reg,      // (B, A, 4)
    const float* __restrict__ anchors,  // (A, 4)  y1,x1,y2,x2
    const float* __restrict__ ann,      // (B, M, 5) x1,y1,x2,y2,label
    float* __restrict__ ws)
{
    __shared__ float s_bx1[M], s_by1[M], s_bx2[M], s_by2[M], s_area[M], s_lab[M];
    __shared__ float s_red[3][4];
    __shared__ float s_stage[4][SLOTS * TILE];   // 4 waves x 4 slots x 1KB = 16 KB

    const int t    = threadIdx.x;
    const int tile = blockIdx.x;
    const int b    = blockIdx.y;
    const int base = tile * TILE;
    const int nA   = min(TILE, A - base);

    // Invalid boxes -> degenerate (zero overlap, +inf area); verified absmax 0.
    if (t < M) {
        const float x1 = ann[(b * M + t) * 5 + 0];
        const float y1 = ann[(b * M + t) * 5 + 1];
        const float x2 = ann[(b * M + t) * 5 + 2];
        const float y2 = ann[(b * M + t) * 5 + 3];
        const float lb = ann[(b * M + t) * 5 + 4];
        const bool v = (lb != -1.0f);
        s_bx1[t]  = v ? x1 :  3e18f;
        s_by1[t]  = v ? y1 :  3e18f;
        s_bx2[t]  = v ? x2 : -3e18f;
        s_by2[t]  = v ? y2 : -3e18f;
        s_area[t] = v ? (x2 - x1) * (y2 - y1) : __builtin_inff();
        s_lab[t]  = lb;
    }
    const float4 an = ((const float4*)anchors)[min(base + t, A - 1)];  // y1,x1,y2,x2
    __syncthreads();

    // Phase A: division-free band classification.
    const float aw  = an.w - an.y;
    const float ah  = an.z - an.x;
    const float aarea = ah * aw;
    float e4 = -1.0f, e5 = -1.0f;
    if (t < nA) {
        #pragma unroll
        for (int j = 0; j < M; ++j) {
            float iw = fmaxf(fminf(an.w, s_bx2[j]) - fmaxf(an.y, s_bx1[j]), 0.0f);
            float ih = fmaxf(fminf(an.z, s_by2[j]) - fmaxf(an.x, s_by1[j]), 0.0f);
            const float inter = iw * ih;
            const float ua = aarea + s_area[j] - inter;
            e4 = fmaxf(e4, fmaf(-0.4f, ua, inter));
            e5 = fmaxf(e5, fmaf(-0.5f, ua, inter));
        }
    }
    const bool pos = (t < nA) && (e5 >= 0.0f);
    const bool ign = (t < nA) && (e4 >= 0.0f) && !pos;

    // Rare pos re-pass: precise argmax + label correction + smooth-L1.
    float cls_part = 0.0f, reg_part = 0.0f, npos_part = 0.0f;
    if (pos) {
        npos_part = 1.0f;
        float best = -2.0f; int arg = 0;
        for (int j = 0; j < M; ++j) {
            float iw = fmaxf(fminf(an.w, s_bx2[j]) - fmaxf(an.y, s_bx1[j]), 0.0f);
            float ih = fmaxf(fminf(an.z, s_by2[j]) - fmaxf(an.x, s_by1[j]), 0.0f);
            const float inter = iw * ih;
            const float ua = fmaxf(aarea + s_area[j] - inter, 1e-8f);
            const float iou = inter / ua;
            if (iou > best) { best = iou; arg = j; }
        }
        const int lab = (int)s_lab[arg];
        const float pl = fminf(fmaxf(cls[((size_t)b * A + base + t) * C + lab], 1e-4f), 1.0f - 1e-4f);
        const float ql = 1.0f - pl;
        // then-term minus the 0.75*f else-term Phase B blindly adds
        cls_part = -0.25f * ql * ql * __log2f(pl) + 0.75f * pl * pl * __log2f(ql);

        const float4 r = ((const float4*)reg)[(size_t)b * A + base + t];
        const float gx1 = s_bx1[arg], gy1 = s_by1[arg];
        const float gx2 = s_bx2[arg], gy2 = s_by2[arg];
        float gw = gx2 - gx1;
        float gh = gy2 - gy1;
        const float gcx = gx1 + 0.5f * gw;
        const float gcy = gy1 + 0.5f * gh;
        const float acx = an.y + 0.5f * aw;
        const float acy = an.x + 0.5f * ah;
        gw = fmaxf(gw, 1.0f);
        gh = fmaxf(gh, 1.0f);
        const float t0 = (gcy - acy) / ah;
        const float t1 = (gcx - acx) / aw;
        const float t2 = __logf(gh / ah);
        const float t3 = __logf(gw / aw);
        const float d0 = fabsf(t0 - r.x);
        const float d1 = fabsf(t1 - r.y);
        const float d2 = fabsf(t2 - r.z);
        const float d3 = fabsf(t3 - r.w);
        const float TH = 1.0f / 9.0f;
        const float SH = 0.5f / 9.0f;
        reg_part = ((d0 <= TH) ? 4.5f * d0 * d0 : d0 - SH)
                 + ((d1 <= TH) ? 4.5f * d1 * d1 : d1 - SH)
                 + ((d2 <= TH) ? 4.5f * d2 * d2 : d2 - SH)
                 + ((d3 <= TH) ? 4.5f * d3 * d3 : d3 - SH);
    }

    // Phase B: unconditional focal stream via per-wave async DMA pipeline.
    // Each wave owns SLOTS private 1KB LDS slots; counted vmcnt keeps SLOTS
    // loads in flight at all times (never drains to 0 until the epilogue).
    const float4* cp = (const float4*)(cls + ((size_t)b * A + base) * C);
    const bool full = (nA == TILE);
    float accA = 0.0f, accB = 0.0f;
    if (full) {
        const int wave = t >> 6;
        const int lane = t & 63;
        float* wbase = &s_stage[wave][0];

        // prologue: fill all slots
        #pragma unroll
        for (int s = 0; s < SLOTS; ++s)
            gload_lds16(cp + (s * TILE + t), wbase + s * TILE);
        SBAR();

        // steady: wait oldest -> consume -> reissue into freed slot
        #pragma unroll
        for (int i = 0; i < QPA - SLOTS; ++i) {
            asm volatile("s_waitcnt vmcnt(3)" ::: "memory");
            SBAR();
            const float4 v = *(const float4*)(wbase + (i & (SLOTS - 1)) * TILE + lane * 4);
            fquad(v, accA, accB);
            SBAR();   // keep the reissue below the consume (lgkm-safe reuse)
            gload_lds16(cp + ((i + SLOTS) * TILE + t), wbase + (i & (SLOTS - 1)) * TILE);
            SBAR();
        }
        // epilogue: drain 3,2,1,0
        asm volatile("s_waitcnt vmcnt(3)" ::: "memory"); SBAR();
        { const float4 v = *(const float4*)(wbase + ((QPA - 4) & (SLOTS - 1)) * TILE + lane * 4); fquad(v, accA, accB); }
        asm volatile("s_waitcnt vmcnt(2)" ::: "memory"); SBAR();
        { const float4 v = *(const float4*)(wbase + ((QPA - 3) & (SLOTS - 1)) * TILE + lane * 4); fquad(v, accA, accB); }
        asm volatile("s_waitcnt vmcnt(1)" ::: "memory"); SBAR();
        { const float4 v = *(const float4*)(wbase + ((QPA - 2) & (SLOTS - 1)) * TILE + lane * 4); fquad(v, accA, accB); }
        asm volatile("s_waitcnt vmcnt(0)" ::: "memory"); SBAR();
        { const float4 v = *(const float4*)(wbase + ((QPA - 1) & (SLOTS - 1)) * TILE + lane * 4); fquad(v, accA, accB); }
    } else {
        const int nquad = nA * QPA;
        for (int k = t; k < nquad; k += TILE) fquad(cp[k], accA, accB);
    }

    // Phase C: rare ignore anchors subtract their own row (L1/L2-hot).
    if (ign) {
        const float4* rp = cp + t * QPA;
        float g0 = 0.0f, g1 = 0.0f;
        #pragma unroll
        for (int j = 0; j < QPA; ++j) fquad(rp[j], g0, g1);
        cls_part += -0.75f * (g0 + g1);
    }
    cls_part += 0.75f * (accA + accB);

    // Block reduction: wave shuffle then cross-wave via LDS.
    for (int off = 32; off > 0; off >>= 1) {
        cls_part  += __shfl_down(cls_part,  off, 64);
        reg_part  += __shfl_down(reg_part,  off, 64);
        npos_part += __shfl_down(npos_part, off, 64);
    }
    const int wave = t >> 6;
    const int lane = t & 63;
    if (lane == 0) {
        s_red[0][wave] = cls_part;
        s_red[1][wave] = reg_part;
        s_red[2][wave] = npos_part;
    }
    __syncthreads();
    if (t == 0) {
        float cs = 0.0f, rs = 0.0f, ns = 0.0f;
        #pragma unroll
        for (int wv = 0; wv < 4; ++wv) {
            cs += s_red[0][wv];
            rs += s_red[1][wv];
            ns += s_red[2][wv];
        }
        atomicAdd(&ws[b],      cs);
        atomicAdd(&ws[8 + b],  rs);
        atomicAdd(&ws[16 + b], ns);
    }
}

__global__ void finalize_kernel(const float* __restrict__ ws,
                                const float* __restrict__ ann,
                                float* __restrict__ out)
{
    const int t = threadIdx.x;  // 64 threads, one wave
    float cls_v = 0.0f, reg_v = 0.0f;
    if (t < B) {
        bool has_valid = false;
        for (int m = 0; m < M; ++m)
            has_valid = has_valid || (ann[t * M * 5 + m * 5 + 4] != -1.0f);
        const float npos = ws[16 + t];
        // cls accumulator is in log2 units -> scale by ln(2)
        const float cs = 0.69314718056f * ws[t] / fmaxf(npos, 1.0f);
        cls_v = has_valid ? cs : 0.0f;
        reg_v = (npos > 0.0f) ? (ws[8 + t] / fmaxf(npos * 4.0f, 1.0f)) : 0.0f;
    }
    for (int off = 32; off > 0; off >>= 1) {
        cls_v += __shfl_down(cls_v, off, 64);
        reg_v += __shfl_down(reg_v, off, 64);
    }
    if (t == 0) {
        out[0] = cls_v * (1.0f / (float)B);
        out[1] = reg_v * (1.0f / (float)B);
    }
}

extern "C" void kernel_launch(void* const* d_in, const int* in_sizes, int n_in,
                              void* d_out, int out_size, void* d_ws, size_t ws_size,
                              hipStream_t stream) {
    const float* cls     = (const float*)d_in[0];
    const float* reg     = (const float*)d_in[1];
    const float* anchors = (const float*)d_in[2];
    const float* ann     = (const float*)d_in[3];
    float* out = (float*)d_out;
    float* ws  = (float*)d_ws;

    init_ws_kernel<<<1, 32, 0, stream>>>(ws);
    focal_main_kernel<<<dim3(NTILES, B), TILE, 0, stream>>>(cls, reg, anchors, ann, ws);
    finalize_kernel<<<1, 64, 0, stream>>>(ws, ann, out);
}

// Round 18
// 32.286 us; speedup vs baseline: 3.6327x; 2.0497x over previous
//
#include <hip/hip_runtime.h>
#include <math.h>

// Problem dims (fixed by setup_inputs)
constexpr int B = 8;
constexpr int A = 49104;
constexpr int C = 80;       // classes
constexpr int M = 32;       // max annotations
constexpr int TILE = 256;   // anchors per block == threads per block
constexpr int NTILES = (A + TILE - 1) / TILE;  // 192
constexpr int WS2 = 8192;   // float offset of per-image partials in ws

// ws layout: slots [(b*NTILES+tile)*4 + {0,1,2}] = per-block {cls(log2), reg, npos}
// (PLAIN STORES, unconditionally written every call -> no init, no atomics);
// ws[WS2 + b*4 + {0,1,2}] = per-image sums (written by reduce_kernel).

__device__ __forceinline__ void focal_quad(const float4 p4, const float wq,
                                           float& accA, float& accB) {
    const float px = fminf(fmaxf(p4.x, 1e-4f), 1.0f - 1e-4f);
    const float py = fminf(fmaxf(p4.y, 1e-4f), 1.0f - 1e-4f);
    const float pz = fminf(fmaxf(p4.z, 1e-4f), 1.0f - 1e-4f);
    const float pw = fminf(fmaxf(p4.w, 1e-4f), 1.0f - 1e-4f);
    accA = fmaf(-wq, px * px * __log2f(1.0f - px), accA);
    accB = fmaf(-wq, py * py * __log2f(1.0f - py), accB);
    accA = fmaf(-wq, pz * pz * __log2f(1.0f - pz), accA);
    accB = fmaf(-wq, pw * pw * __log2f(1.0f - pw), accB);
}

// Identical to the best-measured kernel (R8 bench: 62.2 us) EXCEPT the tail:
// per-block plain stores to private slots instead of 3 atomicAdds into one
// shared 128-B cache line (the one invariant across all six ~62-66 us
// structures; testing atomic-line serialization as the hidden floor).
__global__ __launch_bounds__(TILE, 8) void focal_main_kernel(
    const float* __restrict__ cls,      // (B, A, C)
    const float* __restrict__ reg,      // (B, A, 4)
    const float* __restrict__ anchors,  // (A, 4)  y1,x1,y2,x2
    const float* __restrict__ ann,      // (B, M, 5) x1,y1,x2,y2,label
    float* __restrict__ ws)
{
    __shared__ float s_ann[M][5];
    __shared__ float s_w[TILE];       // 0.75 for pos|neg anchors, 0 for ignore/tail
    __shared__ float s_red[3][4];

    const int t    = threadIdx.x;
    const int tile = blockIdx.x;
    const int b    = blockIdx.y;
    const int base = tile * TILE;
    const int nA   = min(TILE, A - base);

    if (t < M * 5) ((float*)s_ann)[t] = ann[b * M * 5 + t];
    __syncthreads();

    float cls_part  = 0.0f;   // log2 units
    float reg_part  = 0.0f;
    float npos_part = 0.0f;
    float w = 0.0f;

    if (t < nA) {
        const int a = base + t;
        const float4 an = ((const float4*)anchors)[a];  // y1,x1,y2,x2
        const float aw  = an.w - an.y;
        const float ah  = an.z - an.x;
        const float acx = an.y + 0.5f * aw;
        const float acy = an.x + 0.5f * ah;
        const float aarea = ah * aw;

        float best = -2.0f;   // below the -1 sentinel
        int   arg  = 0;
        #pragma unroll
        for (int j = 0; j < M; ++j) {
            const float bx1 = s_ann[j][0];
            const float by1 = s_ann[j][1];
            const float bx2 = s_ann[j][2];
            const float by2 = s_ann[j][3];
            const float lb  = s_ann[j][4];
            float iw = fminf(an.w, bx2) - fmaxf(an.y, bx1);
            float ih = fminf(an.z, by2) - fmaxf(an.x, by1);
            iw = fmaxf(iw, 0.0f);
            ih = fmaxf(ih, 0.0f);
            const float inter = iw * ih;
            const float area  = (bx2 - bx1) * (by2 - by1);
            const float ua    = fmaxf(aarea + area - inter, 1e-8f);
            const float iou   = (lb != -1.0f) ? (inter / ua) : -1.0f;
            if (iou > best) { best = iou; arg = j; }   // strict > == argmax first-occurrence
        }
        const bool pos = best >= 0.5f;
        const bool neg = best <  0.4f;
        w = (pos || neg) ? 0.75f : 0.0f;

        if (pos) {
            npos_part = 1.0f;
            const int lab = (int)s_ann[arg][4];
            // cls correction for the label element (then-term minus the
            // else-term Phase B will blindly add). All in log2 units.
            const float pl = fminf(fmaxf(cls[((size_t)b * A + a) * C + lab], 1e-4f), 1.0f - 1e-4f);
            const float ql = 1.0f - pl;
            cls_part = -0.25f * ql * ql * __log2f(pl) + 0.75f * pl * pl * __log2f(ql);

            // smooth-L1 regression term (natural-log units)
            const float4 r = ((const float4*)reg)[(size_t)b * A + a];
            const float ax1 = s_ann[arg][0];
            const float ay1 = s_ann[arg][1];
            const float ax2 = s_ann[arg][2];
            const float ay2 = s_ann[arg][3];
            float gw = ax2 - ax1;
            float gh = ay2 - ay1;
            const float gcx = ax1 + 0.5f * gw;
            const float gcy = ay1 + 0.5f * gh;
            gw = fmaxf(gw, 1.0f);
            gh = fmaxf(gh, 1.0f);
            const float t0 = (gcy - acy) / ah;
            const float t1 = (gcx - acx) / aw;
            const float t2 = __logf(gh / ah);
            const float t3 = __logf(gw / aw);
            const float d0 = fabsf(t0 - r.x);
            const float d1 = fabsf(t1 - r.y);
            const float d2 = fabsf(t2 - r.z);
            const float d3 = fabsf(t3 - r.w);
            const float TH = 1.0f / 9.0f;
            const float SH = 0.5f / 9.0f;
            reg_part = ((d0 <= TH) ? 4.5f * d0 * d0 : d0 - SH)
                     + ((d1 <= TH) ? 4.5f * d1 * d1 : d1 - SH)
                     + ((d2 <= TH) ? 4.5f * d2 * d2 : d2 - SH)
                     + ((d3 <= TH) ? 4.5f * d3 * d3 : d3 - SH);
        }
    }
    s_w[t] = w;
    __syncthreads();

    // Phase B: branchless focal-BCE "else-branch" stream, batched 5 deep.
    const float4* cp = (const float4*)(cls + ((size_t)b * A + base) * C);
    const int nquad = nA * (C / 4);   // 20 float4 per anchor
    float accA = cls_part, accB = 0.0f;

    int k = t;
    for (; k + 4 * TILE < nquad; k += 5 * TILE) {
        const float4 q0 = cp[k];
        const float4 q1 = cp[k +     TILE];
        const float4 q2 = cp[k + 2 * TILE];
        const float4 q3 = cp[k + 3 * TILE];
        const float4 q4 = cp[k + 4 * TILE];
        const float w0 = s_w[(unsigned)(k)            / 20u];
        const float w1 = s_w[(unsigned)(k +     TILE) / 20u];
        const float w2 = s_w[(unsigned)(k + 2 * TILE) / 20u];
        const float w3 = s_w[(unsigned)(k + 3 * TILE) / 20u];
        const float w4 = s_w[(unsigned)(k + 4 * TILE) / 20u];
        focal_quad(q0, w0, accA, accB);
        focal_quad(q1, w1, accA, accB);
        focal_quad(q2, w2, accA, accB);
        focal_quad(q3, w3, accA, accB);
        focal_quad(q4, w4, accA, accB);
    }
    for (; k < nquad; k += TILE) {
        const float4 q = cp[k];
        const float wq = s_w[(unsigned)k / 20u];
        focal_quad(q, wq, accA, accB);
    }
    cls_part = accA + accB;

    // Block reduction: wave shuffle then cross-wave via LDS.
    for (int off = 32; off > 0; off >>= 1) {
        cls_part  += __shfl_down(cls_part,  off, 64);
        reg_part  += __shfl_down(reg_part,  off, 64);
        npos_part += __shfl_down(npos_part, off, 64);
    }
    const int wave = t >> 6;
    const int lane = t & 63;
    if (lane == 0) {
        s_red[0][wave] = cls_part;
        s_red[1][wave] = reg_part;
        s_red[2][wave] = npos_part;
    }
    __syncthreads();
    if (t == 0) {
        float cs = 0.0f, rs = 0.0f, ns = 0.0f;
        #pragma unroll
        for (int wv = 0; wv < 4; ++wv) {
            cs += s_red[0][wv];
            rs += s_red[1][wv];
            ns += s_red[2][wv];
        }
        // CONTENTION-FREE: plain stores to this block's private slot.
        float* slot = ws + ((size_t)(b * NTILES + tile) << 2);
        slot[0] = cs;
        slot[1] = rs;
        slot[2] = ns;
    }
}

// Per-image reduction of the 192 block slots (8 blocks x 192 threads).
__global__ __launch_bounds__(192) void reduce_kernel(float* __restrict__ ws)
{
    const int b = blockIdx.x;
    const int t = threadIdx.x;    // 0..191 (3 waves)
    const float* slot = ws + ((size_t)(b * NTILES + t) << 2);
    float c = slot[0];
    float r = slot[1];
    float n = slot[2];
    for (int off = 32; off > 0; off >>= 1) {
        c += __shfl_down(c, off, 64);
        r += __shfl_down(r, off, 64);
        n += __shfl_down(n, off, 64);
    }
    __shared__ float red[3][3];
    if ((t & 63) == 0) {
        red[0][t >> 6] = c;
        red[1][t >> 6] = r;
        red[2][t >> 6] = n;
    }
    __syncthreads();
    if (t == 0) {
        ws[WS2 + b * 4 + 0] = red[0][0] + red[0][1] + red[0][2];
        ws[WS2 + b * 4 + 1] = red[1][0] + red[1][1] + red[1][2];
        ws[WS2 + b * 4 + 2] = red[2][0] + red[2][1] + red[2][2];
    }
}

__global__ void finalize_kernel(const float* __restrict__ ws,
                                const float* __restrict__ ann,
                                float* __restrict__ out)
{
    const int t = threadIdx.x;  // 64 threads, one wave
    float cls_v = 0.0f, reg_v = 0.0f;
    if (t < B) {
        bool has_valid = false;
        for (int m = 0; m < M; ++m)
            has_valid = has_valid || (ann[t * M * 5 + m * 5 + 4] != -1.0f);
        const float npos = ws[WS2 + t * 4 + 2];
        // cls accumulator is in log2 units -> scale by ln(2)
        const float cs = 0.69314718056f * ws[WS2 + t * 4 + 0] / fmaxf(npos, 1.0f);
        cls_v = has_valid ? cs : 0.0f;
        reg_v = (npos > 0.0f) ? (ws[WS2 + t * 4 + 1] / fmaxf(npos * 4.0f, 1.0f)) : 0.0f;
    }
    for (int off = 32; off > 0; off >>= 1) {
        cls_v += __shfl_down(cls_v, off, 64);
        reg_v += __shfl_down(reg_v, off, 64);
    }
    if (t == 0) {
        out[0] = cls_v * (1.0f / (float)B);
        out[1] = reg_v * (1.0f / (float)B);
    }
}

extern "C" void kernel_launch(void* const* d_in, const int* in_sizes, int n_in,
                              void* d_out, int out_size, void* d_ws, size_t ws_size,
                              hipStream_t stream) {
    const float* cls     = (const float*)d_in[0];
    const float* reg     = (const float*)d_in[1];
    const float* anchors = (const float*)d_in[2];
    const float* ann     = (const float*)d_in[3];
    float* out = (float*)d_out;
    float* ws  = (float*)d_ws;

    // No init kernel: every ws slot used is unconditionally overwritten
    // (plain stores), so the 0xAA poison never survives into a read.
    focal_main_kernel<<<dim3(NTILES, B), TILE, 0, stream>>>(cls, reg, anchors, ann, ws);
    reduce_kernel<<<B, 192, 0, stream>>>(ws);
    finalize_kernel<<<1, 64, 0, stream>>>(ws, ann, out);
}

// Round 19
// 30.490 us; speedup vs baseline: 3.8466x; 1.0589x over previous
//
#include <hip/hip_runtime.h>
#include <math.h>

// Problem dims (fixed by setup_inputs)
constexpr int B = 8;
constexpr int A = 49104;
constexpr int C = 80;       // classes
constexpr int M = 32;       // max annotations
constexpr int TILE = 256;   // anchors per block == threads per block
constexpr int NTILES = (A + TILE - 1) / TILE;  // 192

// ws layout: slots [(b*NTILES+tile)*4 + {0,1,2}] = per-block {cls(log2), reg, npos}
// (PLAIN STORES, unconditionally written every call -> no init, no atomics).

__device__ __forceinline__ void focal_quad(const float4 p4, const float wq,
                                           float& accA, float& accB) {
    const float px = fminf(fmaxf(p4.x, 1e-4f), 1.0f - 1e-4f);
    const float py = fminf(fmaxf(p4.y, 1e-4f), 1.0f - 1e-4f);
    const float pz = fminf(fmaxf(p4.z, 1e-4f), 1.0f - 1e-4f);
    const float pw = fminf(fmaxf(p4.w, 1e-4f), 1.0f - 1e-4f);
    accA = fmaf(-wq, px * px * __log2f(1.0f - px), accA);
    accB = fmaf(-wq, py * py * __log2f(1.0f - py), accB);
    accA = fmaf(-wq, pz * pz * __log2f(1.0f - pz), accA);
    accB = fmaf(-wq, pw * pw * __log2f(1.0f - pw), accB);
}

// R18-verified main kernel (32.3 us total, absmax 0.0) — UNCHANGED.
// Atomic-free tail: per-block plain stores to private padded slots.
__global__ __launch_bounds__(TILE, 8) void focal_main_kernel(
    const float* __restrict__ cls,      // (B, A, C)
    const float* __restrict__ reg,      // (B, A, 4)
    const float* __restrict__ anchors,  // (A, 4)  y1,x1,y2,x2
    const float* __restrict__ ann,      // (B, M, 5) x1,y1,x2,y2,label
    float* __restrict__ ws)
{
    __shared__ float s_ann[M][5];
    __shared__ float s_w[TILE];       // 0.75 for pos|neg anchors, 0 for ignore/tail
    __shared__ float s_red[3][4];

    const int t    = threadIdx.x;
    const int tile = blockIdx.x;
    const int b    = blockIdx.y;
    const int base = tile * TILE;
    const int nA   = min(TILE, A - base);

    if (t < M * 5) ((float*)s_ann)[t] = ann[b * M * 5 + t];
    __syncthreads();

    float cls_part  = 0.0f;   // log2 units
    float reg_part  = 0.0f;
    float npos_part = 0.0f;
    float w = 0.0f;

    if (t < nA) {
        const int a = base + t;
        const float4 an = ((const float4*)anchors)[a];  // y1,x1,y2,x2
        const float aw  = an.w - an.y;
        const float ah  = an.z - an.x;
        const float acx = an.y + 0.5f * aw;
        const float acy = an.x + 0.5f * ah;
        const float aarea = ah * aw;

        float best = -2.0f;   // below the -1 sentinel
        int   arg  = 0;
        #pragma unroll
        for (int j = 0; j < M; ++j) {
            const float bx1 = s_ann[j][0];
            const float by1 = s_ann[j][1];
            const float bx2 = s_ann[j][2];
            const float by2 = s_ann[j][3];
            const float lb  = s_ann[j][4];
            float iw = fminf(an.w, bx2) - fmaxf(an.y, bx1);
            float ih = fminf(an.z, by2) - fmaxf(an.x, by1);
            iw = fmaxf(iw, 0.0f);
            ih = fmaxf(ih, 0.0f);
            const float inter = iw * ih;
            const float area  = (bx2 - bx1) * (by2 - by1);
            const float ua    = fmaxf(aarea + area - inter, 1e-8f);
            const float iou   = (lb != -1.0f) ? (inter / ua) : -1.0f;
            if (iou > best) { best = iou; arg = j; }   // strict > == argmax first-occurrence
        }
        const bool pos = best >= 0.5f;
        const bool neg = best <  0.4f;
        w = (pos || neg) ? 0.75f : 0.0f;

        if (pos) {
            npos_part = 1.0f;
            const int lab = (int)s_ann[arg][4];
            // cls correction for the label element (then-term minus the
            // else-term Phase B will blindly add). All in log2 units.
            const float pl = fminf(fmaxf(cls[((size_t)b * A + a) * C + lab], 1e-4f), 1.0f - 1e-4f);
            const float ql = 1.0f - pl;
            cls_part = -0.25f * ql * ql * __log2f(pl) + 0.75f * pl * pl * __log2f(ql);

            // smooth-L1 regression term (natural-log units)
            const float4 r = ((const float4*)reg)[(size_t)b * A + a];
            const float ax1 = s_ann[arg][0];
            const float ay1 = s_ann[arg][1];
            const float ax2 = s_ann[arg][2];
            const float ay2 = s_ann[arg][3];
            float gw = ax2 - ax1;
            float gh = ay2 - ay1;
            const float gcx = ax1 + 0.5f * gw;
            const float gcy = ay1 + 0.5f * gh;
            gw = fmaxf(gw, 1.0f);
            gh = fmaxf(gh, 1.0f);
            const float t0 = (gcy - acy) / ah;
            const float t1 = (gcx - acx) / aw;
            const float t2 = __logf(gh / ah);
            const float t3 = __logf(gw / aw);
            const float d0 = fabsf(t0 - r.x);
            const float d1 = fabsf(t1 - r.y);
            const float d2 = fabsf(t2 - r.z);
            const float d3 = fabsf(t3 - r.w);
            const float TH = 1.0f / 9.0f;
            const float SH = 0.5f / 9.0f;
            reg_part = ((d0 <= TH) ? 4.5f * d0 * d0 : d0 - SH)
                     + ((d1 <= TH) ? 4.5f * d1 * d1 : d1 - SH)
                     + ((d2 <= TH) ? 4.5f * d2 * d2 : d2 - SH)
                     + ((d3 <= TH) ? 4.5f * d3 * d3 : d3 - SH);
        }
    }
    s_w[t] = w;
    __syncthreads();

    // Phase B: branchless focal-BCE "else-branch" stream, batched 5 deep.
    const float4* cp = (const float4*)(cls + ((size_t)b * A + base) * C);
    const int nquad = nA * (C / 4);   // 20 float4 per anchor
    float accA = cls_part, accB = 0.0f;

    int k = t;
    for (; k + 4 * TILE < nquad; k += 5 * TILE) {
        const float4 q0 = cp[k];
        const float4 q1 = cp[k +     TILE];
        const float4 q2 = cp[k + 2 * TILE];
        const float4 q3 = cp[k + 3 * TILE];
        const float4 q4 = cp[k + 4 * TILE];
        const float w0 = s_w[(unsigned)(k)            / 20u];
        const float w1 = s_w[(unsigned)(k +     TILE) / 20u];
        const float w2 = s_w[(unsigned)(k + 2 * TILE) / 20u];
        const float w3 = s_w[(unsigned)(k + 3 * TILE) / 20u];
        const float w4 = s_w[(unsigned)(k + 4 * TILE) / 20u];
        focal_quad(q0, w0, accA, accB);
        focal_quad(q1, w1, accA, accB);
        focal_quad(q2, w2, accA, accB);
        focal_quad(q3, w3, accA, accB);
        focal_quad(q4, w4, accA, accB);
    }
    for (; k < nquad; k += TILE) {
        const float4 q = cp[k];
        const float wq = s_w[(unsigned)k / 20u];
        focal_quad(q, wq, accA, accB);
    }
    cls_part = accA + accB;

    // Block reduction: wave shuffle then cross-wave via LDS.
    for (int off = 32; off > 0; off >>= 1) {
        cls_part  += __shfl_down(cls_part,  off, 64);
        reg_part  += __shfl_down(reg_part,  off, 64);
        npos_part += __shfl_down(npos_part, off, 64);
    }
    const int wave = t >> 6;
    const int lane = t & 63;
    if (lane == 0) {
        s_red[0][wave] = cls_part;
        s_red[1][wave] = reg_part;
        s_red[2][wave] = npos_part;
    }
    __syncthreads();
    if (t == 0) {
        float cs = 0.0f, rs = 0.0f, ns = 0.0f;
        #pragma unroll
        for (int wv = 0; wv < 4; ++wv) {
            cs += s_red[0][wv];
            rs += s_red[1][wv];
            ns += s_red[2][wv];
        }
        // CONTENTION-FREE: plain stores to this block's private slot.
        float* slot = ws + ((size_t)(b * NTILES + tile) << 2);
        slot[0] = cs;
        slot[1] = rs;
        slot[2] = ns;
    }
}

// Merged reduce+finalize: one block, 8 waves; wave w reduces image w's 192
// slots (3 slots/lane), then thread 0 combines the 8 images. Saves one
// kernel launch vs the R18 two-kernel tail.
__global__ __launch_bounds__(512) void tail_kernel(
    const float* __restrict__ ws_in,
    const float* __restrict__ ann,
    float* __restrict__ out)
{
    const int t    = threadIdx.x;
    const int b    = t >> 6;        // wave index == image
    const int lane = t & 63;

    float c = 0.0f, r = 0.0f, n = 0.0f;
    #pragma unroll
    for (int s = 0; s < 3; ++s) {
        const int tile = lane * 3 + s;   // 64*3 = 192 slots
        const float* slot = ws_in + ((size_t)(b * NTILES + tile) << 2);
        c += slot[0];
        r += slot[1];
        n += slot[2];
    }
    for (int off = 32; off > 0; off >>= 1) {
        c += __shfl_down(c, off, 64);
        r += __shfl_down(r, off, 64);
        n += __shfl_down(n, off, 64);
    }

    __shared__ float s_cls[B], s_reg[B];
    if (lane == 0) {
        bool has_valid = false;
        for (int m = 0; m < M; ++m)
            has_valid = has_valid || (ann[b * M * 5 + m * 5 + 4] != -1.0f);
        // cls accumulator is in log2 units -> scale by ln(2)
        const float cs = 0.69314718056f * c / fmaxf(n, 1.0f);
        s_cls[b] = has_valid ? cs : 0.0f;
        s_reg[b] = (n > 0.0f) ? (r / fmaxf(n * 4.0f, 1.0f)) : 0.0f;
    }
    __syncthreads();
    if (t == 0) {
        float cv = 0.0f, rv = 0.0f;
        #pragma unroll
        for (int i = 0; i < B; ++i) { cv += s_cls[i]; rv += s_reg[i]; }
        out[0] = cv * (1.0f / (float)B);
        out[1] = rv * (1.0f / (float)B);
    }
}

extern "C" void kernel_launch(void* const* d_in, const int* in_sizes, int n_in,
                              void* d_out, int out_size, void* d_ws, size_t ws_size,
                              hipStream_t stream) {
    const float* cls     = (const float*)d_in[0];
    const float* reg     = (const float*)d_in[1];
    const float* anchors = (const float*)d_in[2];
    const float* ann     = (const float*)d_in[3];
    float* out = (float*)d_out;
    float* ws  = (float*)d_ws;

    // No init kernel: every ws slot used is unconditionally overwritten
    // (plain stores), so the 0xAA poison never survives into a read.
    focal_main_kernel<<<dim3(NTILES, B), TILE, 0, stream>>>(cls, reg, anchors, ann, ws);
    tail_kernel<<<1, 512, 0, stream>>>(ws, ann, out);
}